// Round 14
// baseline (327.044 us; speedup 1.0000x reference)
//
#include <hip/hip_runtime.h>
#include <hip/hip_bf16.h>
#include <hip/hip_fp16.h>
#include <math.h>

// ---------------------------------------------------------------------------
// GCN 3-layer + mean-pool + linear head + softmax, fp32 in/out.
// Padded-bucket adjacency (64 slots/node, self-loop slot 0):
//   k_count:    pure atomic count (full E) — saturates memory-side atomics
//   k_fillgemm1: fill (pure computed-address writes) ∥ layer-1 GEMM
//                (fp32 features direct, dinv=rsqrt(cnt+1) applied; cnt final)
// Gathers scale-free, bucket meta hoisted to registers (coalesced load +
// __shfl) so xwh row loads pipeline. Layer-1/2 pooling rides in the gemm2/3
// dispatches; only layer-3 pool + head remain at the tail.
// fp16 pipeline, MFMA v_mfma_f32_16x16x32_f16, fp32 accum.
// ---------------------------------------------------------------------------

#define F 64
#define NGRAPHS 128
#define NCLASSES 10
#define FCAT 192
#define PSPLIT 16
#define CAP 64            // slots per node (deg+1; Poisson(16) -> safe)

typedef _Float16 f16x8 __attribute__((ext_vector_type(8)));
typedef float f32x4 __attribute__((ext_vector_type(4)));

// ---- prep: cnt=0, self-loop meta, W->Wt fp16 transposed -------------------
__global__ void k_prep(const float* __restrict__ W1, const float* __restrict__ W2,
                       const float* __restrict__ W3,
                       int* __restrict__ cnt, int* __restrict__ meta,
                       __half* __restrict__ Wt, int n) {
    int tid = blockIdx.x * blockDim.x + threadIdx.x;
    int stride = gridDim.x * blockDim.x;
    for (int i = tid; i < n; i += stride) {
        cnt[i] = 0;
        meta[(size_t)i << 6] = i;          // self-loop at slot 0
    }
    for (int t = tid; t < 3 * 4096; t += stride) {
        int w = t >> 12, idx = t & 4095;
        int c = idx >> 6, k = idx & 63;
        const float* W = (w == 0) ? W1 : (w == 1) ? W2 : W3;
        Wt[t] = __float2half(W[k * F + c]);
    }
}

// ---- pure atomic count: slot[e] = within-dest order -----------------------
__global__ __launch_bounds__(256) void k_count(const int* __restrict__ col,
                                               int* __restrict__ cnt,
                                               int* __restrict__ slot, int E) {
    int e = blockIdx.x * 256 + threadIdx.x;
    if (e < E) slot[e] = atomicAdd(&cnt[col[e]], 1);
}

// ---- fused: [0,gemmBlocks) layer-1 GEMM (scaled); rest: pure-write fill ---
__global__ __launch_bounds__(256) void k_fillgemm1(
        const int* __restrict__ row, const int* __restrict__ col,
        const int* __restrict__ slot, int E, int* __restrict__ meta,
        const float* __restrict__ features, const __half* __restrict__ Wt,
        const int* __restrict__ cnt, __half* __restrict__ xwh, int n,
        int gemmBlocks) {
    if (blockIdx.x >= gemmBlocks) {
        int e = (blockIdx.x - gemmBlocks) * 256 + threadIdx.x;
        if (e < E) meta[((size_t)col[e] << 6) + 1 + slot[e]] = row[e];
        return;
    }
    // layer-1 GEMM tile (16 rows), fp32 features -> fp16 frags, scaled store
    int wid = (int)((blockIdx.x * 256 + threadIdx.x) >> 6);
    int lane = threadIdx.x & 63;
    int r0 = wid * 16;
    if (r0 >= n) return;
    int rA = min(r0 + (lane & 15), n - 1);
    int kOff = (lane >> 4) * 8;
    const float4* xp = (const float4*)(features + (size_t)rA * F + kOff);
    float4 fa = xp[0], fb = xp[1];
    float4 fc = xp[8], fd = xp[9];
    f16x8 a0 = {(_Float16)fa.x, (_Float16)fa.y, (_Float16)fa.z, (_Float16)fa.w,
                (_Float16)fb.x, (_Float16)fb.y, (_Float16)fb.z, (_Float16)fb.w};
    f16x8 a1 = {(_Float16)fc.x, (_Float16)fc.y, (_Float16)fc.z, (_Float16)fc.w,
                (_Float16)fd.x, (_Float16)fd.y, (_Float16)fd.z, (_Float16)fd.w};
    f32x4 acc0, acc1, acc2, acc3;
#define DO_CT(CT, ACC) { \
        const f16x8* bp = (const f16x8*)(Wt + (((CT) * 16 + (lane & 15)) << 6) + kOff); \
        f16x8 b0 = bp[0], b1 = bp[4]; \
        f32x4 c = {0.f, 0.f, 0.f, 0.f}; \
        c = __builtin_amdgcn_mfma_f32_16x16x32_f16(a0, b0, c, 0, 0, 0); \
        c = __builtin_amdgcn_mfma_f32_16x16x32_f16(a1, b1, c, 0, 0, 0); \
        ACC = c; }
    DO_CT(0, acc0) DO_CT(1, acc1) DO_CT(2, acc2) DO_CT(3, acc3)
#undef DO_CT
    int rBase = r0 + ((lane >> 4) << 2);
    int q0 = min(rBase + 0, n - 1), q1 = min(rBase + 1, n - 1);
    int q2 = min(rBase + 2, n - 1), q3 = min(rBase + 3, n - 1);
    float d0 = rsqrtf((float)(cnt[q0] + 1));
    float d1 = rsqrtf((float)(cnt[q1] + 1));
    float d2 = rsqrtf((float)(cnt[q2] + 1));
    float d3 = rsqrtf((float)(cnt[q3] + 1));
    int cl = lane & 15;
#define ST_CT(CT, ACC) { \
        __half* op = xwh + (size_t)rBase * F + (CT) * 16 + cl; \
        if (rBase + 0 < n) op[0 * F] = __float2half(ACC.x * d0); \
        if (rBase + 1 < n) op[1 * F] = __float2half(ACC.y * d1); \
        if (rBase + 2 < n) op[2 * F] = __float2half(ACC.z * d2); \
        if (rBase + 3 < n) op[3 * F] = __float2half(ACC.w * d3); }
    ST_CT(0, acc0) ST_CT(1, acc1) ST_CT(2, acc2) ST_CT(3, acc3)
#undef ST_CT
}

// ---- gemm (layers 2,3) with pool of the PREVIOUS layer riding along -------
// blocks [0,gemmBlocks): xw' = (x@W)*rsqrt(cnt+1)
// blocks [gemmBlocks,+2048): pool poolSrc into pooledPart[...][layerOff+f]
__global__ __launch_bounds__(256) void k_gemmpool(
        const __half* __restrict__ xh, const __half* __restrict__ Wt,
        const int* __restrict__ cnt, __half* __restrict__ xwh, int n,
        int gemmBlocks,
        const __half* __restrict__ poolSrc, const int* __restrict__ batch,
        float* __restrict__ pooledPart, int layerOff) {
    if (blockIdx.x >= gemmBlocks) {
        int b = blockIdx.x - gemmBlocks;
        int g = b >> 4, part = b & 15;
        int lo = 0, hi = n;
        while (lo < hi) { int m = (lo + hi) >> 1; if (batch[m] < g) lo = m + 1; else hi = m; }
        int s0 = lo;
        lo = s0; hi = n;
        while (lo < hi) { int m = (lo + hi) >> 1; if (batch[m] < g + 1) lo = m + 1; else hi = m; }
        int e0 = lo;
        int len = e0 - s0;
        int chunk = (len + PSPLIT - 1) / PSPLIT;
        int r0 = s0 + part * chunk;
        int r1 = min(r0 + chunk, e0);
        __shared__ float red[256];
        int f = threadIdx.x & 63, sub = threadIdx.x >> 6;
        float s = 0.0f;
        for (int i = r0 + sub; i < r1; i += 4)
            s += __half2float(poolSrc[(size_t)i * F + f]);
        red[threadIdx.x] = s;
        __syncthreads();
        if (threadIdx.x < 64) {
            float t = red[f] + red[f + 64] + red[f + 128] + red[f + 192];
            pooledPart[(size_t)(part * NGRAPHS + g) * FCAT + layerOff + f] = t;
        }
        return;
    }
    int wid = (int)((blockIdx.x * 256 + threadIdx.x) >> 6);
    int lane = threadIdx.x & 63;
    int r0 = wid * 16;
    if (r0 >= n) return;
    int rA = min(r0 + (lane & 15), n - 1);
    int kOff = (lane >> 4) * 8;
    const f16x8* ap = (const f16x8*)(xh + (size_t)rA * F + kOff);
    f16x8 a0 = ap[0];
    f16x8 a1 = ap[4];
    f32x4 acc0, acc1, acc2, acc3;
#define DO_CT(CT, ACC) { \
        const f16x8* bp = (const f16x8*)(Wt + (((CT) * 16 + (lane & 15)) << 6) + kOff); \
        f16x8 b0 = bp[0], b1 = bp[4]; \
        f32x4 c = {0.f, 0.f, 0.f, 0.f}; \
        c = __builtin_amdgcn_mfma_f32_16x16x32_f16(a0, b0, c, 0, 0, 0); \
        c = __builtin_amdgcn_mfma_f32_16x16x32_f16(a1, b1, c, 0, 0, 0); \
        ACC = c; }
    DO_CT(0, acc0) DO_CT(1, acc1) DO_CT(2, acc2) DO_CT(3, acc3)
#undef DO_CT
    int rBase = r0 + ((lane >> 4) << 2);
    int q0 = min(rBase + 0, n - 1), q1 = min(rBase + 1, n - 1);
    int q2 = min(rBase + 2, n - 1), q3 = min(rBase + 3, n - 1);
    float d0 = rsqrtf((float)(cnt[q0] + 1));
    float d1 = rsqrtf((float)(cnt[q1] + 1));
    float d2 = rsqrtf((float)(cnt[q2] + 1));
    float d3 = rsqrtf((float)(cnt[q3] + 1));
    int cl = lane & 15;
#define ST_CT(CT, ACC) { \
        __half* op = xwh + (size_t)rBase * F + (CT) * 16 + cl; \
        if (rBase + 0 < n) op[0 * F] = __float2half(ACC.x * d0); \
        if (rBase + 1 < n) op[1 * F] = __float2half(ACC.y * d1); \
        if (rBase + 2 < n) op[2 * F] = __float2half(ACC.z * d2); \
        if (rBase + 3 < n) op[3 * F] = __float2half(ACC.w * d3); }
    ST_CT(0, acc0) ST_CT(1, acc1) ST_CT(2, acc2) ST_CT(3, acc3)
#undef ST_CT
}

// ---- standalone pool (layer 3), 256 threads, LDS sub-reduce ---------------
__global__ __launch_bounds__(256) void k_pool(const __half* __restrict__ src,
                                              const int* __restrict__ batch, int n,
                                              float* __restrict__ pooledPart,
                                              int layerOff) {
    int g = blockIdx.x >> 4, part = blockIdx.x & 15;
    int lo = 0, hi = n;
    while (lo < hi) { int m = (lo + hi) >> 1; if (batch[m] < g) lo = m + 1; else hi = m; }
    int s0 = lo;
    lo = s0; hi = n;
    while (lo < hi) { int m = (lo + hi) >> 1; if (batch[m] < g + 1) lo = m + 1; else hi = m; }
    int e0 = lo;
    int len = e0 - s0;
    int chunk = (len + PSPLIT - 1) / PSPLIT;
    int r0 = s0 + part * chunk;
    int r1 = min(r0 + chunk, e0);
    __shared__ float red[256];
    int f = threadIdx.x & 63, sub = threadIdx.x >> 6;
    float s = 0.0f;
    for (int i = r0 + sub; i < r1; i += 4)
        s += __half2float(src[(size_t)i * F + f]);
    red[threadIdx.x] = s;
    __syncthreads();
    if (threadIdx.x < 64) {
        float t = red[f] + red[f + 64] + red[f + 128] + red[f + 192];
        pooledPart[(size_t)(part * NGRAPHS + g) * FCAT + layerOff + f] = t;
    }
}

// out[v] = relu( dinv[v] * sum_{r in bucket[v]} xw'[r] + b ), fp16 out.
__global__ __launch_bounds__(256) void k_gather(const __half* __restrict__ xwh,
                                                const int* __restrict__ meta,
                                                const int* __restrict__ cnt,
                                                const float* __restrict__ bias,
                                                __half* __restrict__ out, int n) {
    int wid = (int)((blockIdx.x * blockDim.x + threadIdx.x) >> 6);
    if (wid >= n) return;
    int lane = threadIdx.x & 63;
    int g = lane >> 4, s = lane & 15;
    int cv = cnt[wid] + 1;               // deg + self
    size_t base = (size_t)wid << 6;
    int myMeta = meta[base + (lane < cv ? lane : 0)];
    float ax = 0.0f, ay = 0.0f, az = 0.0f, aw = 0.0f;
    for (int i = g; i < cv; i += 4) {
        int r = __shfl(myMeta, i);
        uint2 v = *((const uint2*)(xwh + ((size_t)r << 6)) + s);
        __half2 h0 = *reinterpret_cast<const __half2*>(&v.x);
        __half2 h1 = *reinterpret_cast<const __half2*>(&v.y);
        float2 f0 = __half22float2(h0);
        float2 f1 = __half22float2(h1);
        ax += f0.x; ay += f0.y; az += f1.x; aw += f1.y;
    }
#pragma unroll
    for (int m = 16; m <= 32; m <<= 1) {
        ax += __shfl_xor(ax, m);
        ay += __shfl_xor(ay, m);
        az += __shfl_xor(az, m);
        aw += __shfl_xor(aw, m);
    }
    if (g == 0) {
        float dc = rsqrtf((float)cv);
        float4 bv = ((const float4*)bias)[s];
        __half2 h0 = __floats2half2_rn(fmaxf(fmaf(ax, dc, bv.x), 0.0f),
                                       fmaxf(fmaf(ay, dc, bv.y), 0.0f));
        __half2 h1 = __floats2half2_rn(fmaxf(fmaf(az, dc, bv.z), 0.0f),
                                       fmaxf(fmaf(aw, dc, bv.w), 0.0f));
        __half2* op = (__half2*)(out + ((size_t)wid << 6) + (s << 2));
        op[0] = h0; op[1] = h1;
    }
}

// one block per graph: reduce 16 partials -> pooled (LDS), logits, softmax
__global__ __launch_bounds__(192) void k_head(const float* __restrict__ pooledPart,
                                              const int* __restrict__ batch, int n,
                                              const float* __restrict__ Wf,
                                              const float* __restrict__ bf,
                                              float* __restrict__ out) {
    int g = blockIdx.x;
    __shared__ float pool[FCAT];
    __shared__ float lg[NCLASSES];
    int f = threadIdx.x;
    float s = 0.0f;
#pragma unroll
    for (int p = 0; p < PSPLIT; ++p)
        s += pooledPart[(size_t)(p * NGRAPHS + g) * FCAT + f];
    int lo = 0, hi = n;
    while (lo < hi) { int m = (lo + hi) >> 1; if (batch[m] < g) lo = m + 1; else hi = m; }
    int s0 = lo;
    lo = s0; hi = n;
    while (lo < hi) { int m = (lo + hi) >> 1; if (batch[m] < g + 1) lo = m + 1; else hi = m; }
    float invc = 1.0f / fmaxf((float)(lo - s0), 1.0f);
    pool[f] = s * invc;
    __syncthreads();
    if (f < NCLASSES) {
        float acc = bf[f];
        for (int k = 0; k < FCAT; ++k) acc = fmaf(pool[k], Wf[k * NCLASSES + f], acc);
        lg[f] = acc;
    }
    __syncthreads();
    if (f == 0) {
        float mx = lg[0];
#pragma unroll
        for (int c = 1; c < NCLASSES; ++c) mx = fmaxf(mx, lg[c]);
        float ss = 0.0f;
        float e[NCLASSES];
#pragma unroll
        for (int c = 0; c < NCLASSES; ++c) { e[c] = expf(lg[c] - mx); ss += e[c]; }
        float inv = 1.0f / ss;
#pragma unroll
        for (int c = 0; c < NCLASSES; ++c) out[g * NCLASSES + c] = e[c] * inv;
    }
}

// ---------------------------------------------------------------------------

extern "C" void kernel_launch(void* const* d_in, const int* in_sizes, int n_in,
                              void* d_out, int out_size, void* d_ws, size_t ws_size,
                              hipStream_t stream) {
    const float* features = (const float*)d_in[0];
    const int*   edge     = (const int*)d_in[1];
    const int*   batch    = (const int*)d_in[2];
    const float* W1 = (const float*)d_in[3]; const float* b1 = (const float*)d_in[4];
    const float* W2 = (const float*)d_in[5]; const float* b2 = (const float*)d_in[6];
    const float* W3 = (const float*)d_in[7]; const float* b3 = (const float*)d_in[8];
    const float* Wf = (const float*)d_in[9]; const float* bf = (const float*)d_in[10];
    float* out = (float*)d_out;

    const int n = in_sizes[0] / F;   // 100000
    const int E = in_sizes[1] / 2;   // 1600000
    const int* row = edge;
    const int* col = edge + E;

    // workspace layout
    __half* x0h   = (__half*)d_ws;                     // [n*64] layer3 out
    __half* bufAh = x0h + (size_t)n * F;               // [n*64] layer1 out
    __half* bufBh = bufAh + (size_t)n * F;             // [n*64] layer2 out
    __half* xwh   = bufBh + (size_t)n * F;             // [n*64]
    __half* Wt    = xwh + (size_t)n * F;               // [3*64*64]
    int*    meta  = (int*)(Wt + 3 * F * F);            // [n*CAP]
    int*    slot  = meta + (size_t)n * CAP;            // [E]
    int*    cnt   = slot + E;                          // [n]
    float*  pooledPart = (float*)(cnt + n);            // [16*128*192]

    const int BT = 256;
    int gE  = (E + BT - 1) / BT;           // 6250 count/fill blocks
    int gW  = (n + 3) / 4;                 // gather grid (4 nodes/block)
    int gT  = ((n + 15) / 16 + 3) / 4;     // gemm grid (4 tiles/block)
    const int PB = NGRAPHS * PSPLIT;       // 2048 pool blocks

    // ---- build ----
    k_prep<<<256, BT, 0, stream>>>(W1, W2, W3, cnt, meta, Wt, n);
    k_count<<<gE, BT, 0, stream>>>(col, cnt, slot, E);
    k_fillgemm1<<<gT + gE, BT, 0, stream>>>(row, col, slot, E, meta,
                                            features, Wt, cnt, xwh, n, gT);

    // ---- layer 1 gather ----
    k_gather<<<gW, BT, 0, stream>>>(xwh, meta, cnt, b1, bufAh, n);

    // ---- layer 2 gemm ∥ pool(layer1) ----
    k_gemmpool<<<gT + PB, BT, 0, stream>>>(bufAh, Wt + 4096, cnt, xwh, n, gT,
                                           bufAh, batch, pooledPart, 0);
    k_gather<<<gW, BT, 0, stream>>>(xwh, meta, cnt, b2, bufBh, n);

    // ---- layer 3 gemm ∥ pool(layer2) ----
    k_gemmpool<<<gT + PB, BT, 0, stream>>>(bufBh, Wt + 8192, cnt, xwh, n, gT,
                                           bufBh, batch, pooledPart, F);
    k_gather<<<gW, BT, 0, stream>>>(xwh, meta, cnt, b3, x0h, n);

    // ---- pool(layer3) + head ----
    k_pool<<<PB, BT, 0, stream>>>(x0h, batch, n, pooledPart, 2 * F);
    k_head<<<NGRAPHS, FCAT, 0, stream>>>(pooledPart, batch, n, Wf, bf, out);
}

// Round 15
// 303.551 us; speedup vs baseline: 1.0774x; 1.0774x over previous
//
#include <hip/hip_runtime.h>
#include <hip/hip_bf16.h>
#include <hip/hip_fp16.h>
#include <math.h>

// ---------------------------------------------------------------------------
// GCN 3-layer + mean-pool + linear head + softmax, fp32 in/out.
// Padded-bucket adjacency (64 slots/node, self-loop slot 0):
//   k_cntgemm1: atomic count ∥ layer-1 GEMM (block-modulo interleave, gemm
//               stores UNSCALED since cnt isn't final)
//   k_fillscale: fill (computed-address writes) ∥ xwh *= rsqrt(cnt+1) ∥
//                self-loop meta writes
// Gathers: 8 groups x 8 lanes x 16B loads, bucket meta hoisted to registers
// (predicated coalesced load + __shfl). Pool of layer k rides in gemm k+1.
// fp16 pipeline, MFMA v_mfma_f32_16x16x32_f16, fp32 accum.
// ---------------------------------------------------------------------------

#define F 64
#define NGRAPHS 128
#define NCLASSES 10
#define FCAT 192
#define PSPLIT 16
#define CAP 64            // slots per node (deg+1; Poisson(16) -> safe)

typedef _Float16 f16x8 __attribute__((ext_vector_type(8)));
typedef float f32x4 __attribute__((ext_vector_type(4)));

// ---- prep: cnt=0, W->Wt fp16 transposed ----------------------------------
__global__ void k_prep(const float* __restrict__ W1, const float* __restrict__ W2,
                       const float* __restrict__ W3,
                       int* __restrict__ cnt, __half* __restrict__ Wt, int n) {
    int tid = blockIdx.x * blockDim.x + threadIdx.x;
    int stride = gridDim.x * blockDim.x;
    for (int i = tid; i < n; i += stride) cnt[i] = 0;
    for (int t = tid; t < 3 * 4096; t += stride) {
        int w = t >> 12, idx = t & 4095;
        int c = idx >> 6, k = idx & 63;
        const float* W = (w == 0) ? W1 : (w == 1) ? W2 : W3;
        Wt[t] = __float2half(W[k * F + c]);
    }
}

// ---- count ∥ layer-1 GEMM, modulo-interleaved ----------------------------
// blocks with b%5==4 && b/5<gT run a gemm tile (unscaled store); all others
// count edges: cidx = b - min(b/5, gT).
__global__ __launch_bounds__(256) void k_cntgemm1(
        const int* __restrict__ col, int* __restrict__ cnt, int* __restrict__ slot,
        int E, const float* __restrict__ features, const __half* __restrict__ Wt,
        __half* __restrict__ xwh, int n, int gT) {
    int k5 = blockIdx.x / 5, r5 = blockIdx.x % 5;
    if (!(r5 == 4 && k5 < gT)) {
        int cidx = blockIdx.x - min(k5, gT);
        int e = cidx * 256 + threadIdx.x;
        if (e < E) slot[e] = atomicAdd(&cnt[col[e]], 1);
        return;
    }
    // layer-1 GEMM tile (16 rows), fp32 features -> fp16 frags, UNSCALED
    int wid = (int)((k5 * 256 + threadIdx.x) >> 6);
    int lane = threadIdx.x & 63;
    int r0 = wid * 16;
    if (r0 >= n) return;
    int rA = min(r0 + (lane & 15), n - 1);
    int kOff = (lane >> 4) * 8;
    const float4* xp = (const float4*)(features + (size_t)rA * F + kOff);
    float4 fa = xp[0], fb = xp[1];
    float4 fc = xp[8], fd = xp[9];
    f16x8 a0 = {(_Float16)fa.x, (_Float16)fa.y, (_Float16)fa.z, (_Float16)fa.w,
                (_Float16)fb.x, (_Float16)fb.y, (_Float16)fb.z, (_Float16)fb.w};
    f16x8 a1 = {(_Float16)fc.x, (_Float16)fc.y, (_Float16)fc.z, (_Float16)fc.w,
                (_Float16)fd.x, (_Float16)fd.y, (_Float16)fd.z, (_Float16)fd.w};
    f32x4 acc0, acc1, acc2, acc3;
#define DO_CT(CT, ACC) { \
        const f16x8* bp = (const f16x8*)(Wt + (((CT) * 16 + (lane & 15)) << 6) + kOff); \
        f16x8 b0 = bp[0], b1 = bp[4]; \
        f32x4 c = {0.f, 0.f, 0.f, 0.f}; \
        c = __builtin_amdgcn_mfma_f32_16x16x32_f16(a0, b0, c, 0, 0, 0); \
        c = __builtin_amdgcn_mfma_f32_16x16x32_f16(a1, b1, c, 0, 0, 0); \
        ACC = c; }
    DO_CT(0, acc0) DO_CT(1, acc1) DO_CT(2, acc2) DO_CT(3, acc3)
#undef DO_CT
    int rBase = r0 + ((lane >> 4) << 2);
    int cl = lane & 15;
#define ST_CT(CT, ACC) { \
        __half* op = xwh + (size_t)rBase * F + (CT) * 16 + cl; \
        if (rBase + 0 < n) op[0 * F] = __float2half(ACC.x); \
        if (rBase + 1 < n) op[1 * F] = __float2half(ACC.y); \
        if (rBase + 2 < n) op[2 * F] = __float2half(ACC.z); \
        if (rBase + 3 < n) op[3 * F] = __float2half(ACC.w); }
    ST_CT(0, acc0) ST_CT(1, acc1) ST_CT(2, acc2) ST_CT(3, acc3)
#undef ST_CT
}

// ---- fill ∥ scale xwh ∥ self-loop meta ------------------------------------
__global__ __launch_bounds__(256) void k_fillscale(
        const int* __restrict__ row, const int* __restrict__ col,
        const int* __restrict__ slot, int E, int* __restrict__ meta,
        const int* __restrict__ cnt, __half* __restrict__ xwh, int n,
        int fillBlocks, int scaleBlocks) {
    int b = blockIdx.x;
    if (b < fillBlocks) {
        int e = b * 256 + threadIdx.x;
        if (e < E) meta[((size_t)col[e] << 6) + 1 + slot[e]] = row[e];
    } else if (b < fillBlocks + scaleBlocks) {
        int t = (b - fillBlocks) * 256 + threadIdx.x;
        if (t < n * 8) {                       // 8 x 16B per row
            int r = t >> 3;
            float d = rsqrtf((float)(cnt[r] + 1));
            uint4* p = (uint4*)xwh + t;
            uint4 v = *p;
            __half2* h = (__half2*)&v;
#pragma unroll
            for (int q = 0; q < 4; ++q) {
                float2 f = __half22float2(h[q]);
                h[q] = __floats2half2_rn(f.x * d, f.y * d);
            }
            *p = v;
        }
    } else {
        int i = (b - fillBlocks - scaleBlocks) * 256 + threadIdx.x;
        if (i < n) meta[(size_t)i << 6] = i;   // self-loop slot 0
    }
}

// ---- gemm (layers 2,3) with pool of the PREVIOUS layer riding along -------
__global__ __launch_bounds__(256) void k_gemmpool(
        const __half* __restrict__ xh, const __half* __restrict__ Wt,
        const int* __restrict__ cnt, __half* __restrict__ xwh, int n,
        int gemmBlocks,
        const __half* __restrict__ poolSrc, const int* __restrict__ batch,
        float* __restrict__ pooledPart, int layerOff) {
    if (blockIdx.x >= gemmBlocks) {
        int b = blockIdx.x - gemmBlocks;
        int g = b >> 4, part = b & 15;
        int lo = 0, hi = n;
        while (lo < hi) { int m = (lo + hi) >> 1; if (batch[m] < g) lo = m + 1; else hi = m; }
        int s0 = lo;
        lo = s0; hi = n;
        while (lo < hi) { int m = (lo + hi) >> 1; if (batch[m] < g + 1) lo = m + 1; else hi = m; }
        int e0 = lo;
        int len = e0 - s0;
        int chunk = (len + PSPLIT - 1) / PSPLIT;
        int r0 = s0 + part * chunk;
        int r1 = min(r0 + chunk, e0);
        __shared__ float red[256];
        int f = threadIdx.x & 63, sub = threadIdx.x >> 6;
        float s = 0.0f;
        for (int i = r0 + sub; i < r1; i += 4)
            s += __half2float(poolSrc[(size_t)i * F + f]);
        red[threadIdx.x] = s;
        __syncthreads();
        if (threadIdx.x < 64) {
            float t = red[f] + red[f + 64] + red[f + 128] + red[f + 192];
            pooledPart[(size_t)(part * NGRAPHS + g) * FCAT + layerOff + f] = t;
        }
        return;
    }
    int wid = (int)((blockIdx.x * 256 + threadIdx.x) >> 6);
    int lane = threadIdx.x & 63;
    int r0 = wid * 16;
    if (r0 >= n) return;
    int rA = min(r0 + (lane & 15), n - 1);
    int kOff = (lane >> 4) * 8;
    const f16x8* ap = (const f16x8*)(xh + (size_t)rA * F + kOff);
    f16x8 a0 = ap[0];
    f16x8 a1 = ap[4];
    f32x4 acc0, acc1, acc2, acc3;
#define DO_CT(CT, ACC) { \
        const f16x8* bp = (const f16x8*)(Wt + (((CT) * 16 + (lane & 15)) << 6) + kOff); \
        f16x8 b0 = bp[0], b1 = bp[4]; \
        f32x4 c = {0.f, 0.f, 0.f, 0.f}; \
        c = __builtin_amdgcn_mfma_f32_16x16x32_f16(a0, b0, c, 0, 0, 0); \
        c = __builtin_amdgcn_mfma_f32_16x16x32_f16(a1, b1, c, 0, 0, 0); \
        ACC = c; }
    DO_CT(0, acc0) DO_CT(1, acc1) DO_CT(2, acc2) DO_CT(3, acc3)
#undef DO_CT
    int rBase = r0 + ((lane >> 4) << 2);
    int q0 = min(rBase + 0, n - 1), q1 = min(rBase + 1, n - 1);
    int q2 = min(rBase + 2, n - 1), q3 = min(rBase + 3, n - 1);
    float d0 = rsqrtf((float)(cnt[q0] + 1));
    float d1 = rsqrtf((float)(cnt[q1] + 1));
    float d2 = rsqrtf((float)(cnt[q2] + 1));
    float d3 = rsqrtf((float)(cnt[q3] + 1));
    int cl = lane & 15;
#define ST_CT(CT, ACC) { \
        __half* op = xwh + (size_t)rBase * F + (CT) * 16 + cl; \
        if (rBase + 0 < n) op[0 * F] = __float2half(ACC.x * d0); \
        if (rBase + 1 < n) op[1 * F] = __float2half(ACC.y * d1); \
        if (rBase + 2 < n) op[2 * F] = __float2half(ACC.z * d2); \
        if (rBase + 3 < n) op[3 * F] = __float2half(ACC.w * d3); }
    ST_CT(0, acc0) ST_CT(1, acc1) ST_CT(2, acc2) ST_CT(3, acc3)
#undef ST_CT
}

// ---- standalone pool (layer 3) --------------------------------------------
__global__ __launch_bounds__(256) void k_pool(const __half* __restrict__ src,
                                              const int* __restrict__ batch, int n,
                                              float* __restrict__ pooledPart,
                                              int layerOff) {
    int g = blockIdx.x >> 4, part = blockIdx.x & 15;
    int lo = 0, hi = n;
    while (lo < hi) { int m = (lo + hi) >> 1; if (batch[m] < g) lo = m + 1; else hi = m; }
    int s0 = lo;
    lo = s0; hi = n;
    while (lo < hi) { int m = (lo + hi) >> 1; if (batch[m] < g + 1) lo = m + 1; else hi = m; }
    int e0 = lo;
    int len = e0 - s0;
    int chunk = (len + PSPLIT - 1) / PSPLIT;
    int r0 = s0 + part * chunk;
    int r1 = min(r0 + chunk, e0);
    __shared__ float red[256];
    int f = threadIdx.x & 63, sub = threadIdx.x >> 6;
    float s = 0.0f;
    for (int i = r0 + sub; i < r1; i += 4)
        s += __half2float(src[(size_t)i * F + f]);
    red[threadIdx.x] = s;
    __syncthreads();
    if (threadIdx.x < 64) {
        float t = red[f] + red[f + 64] + red[f + 128] + red[f + 192];
        pooledPart[(size_t)(part * NGRAPHS + g) * FCAT + layerOff + f] = t;
    }
}

// out[v] = relu( dinv[v] * sum_{r in bucket[v]} xw'[r] + b ), fp16 out.
// 8 groups x 8 lanes x 16B loads; meta hoisted (predicated) + __shfl.
__global__ __launch_bounds__(256) void k_gather(const __half* __restrict__ xwh,
                                                const int* __restrict__ meta,
                                                const int* __restrict__ cnt,
                                                const float* __restrict__ bias,
                                                __half* __restrict__ out, int n) {
    int wid = (int)((blockIdx.x * blockDim.x + threadIdx.x) >> 6);
    if (wid >= n) return;
    int lane = threadIdx.x & 63;
    int g = lane >> 3, s = lane & 7;
    int cv = cnt[wid] + 1;               // deg + self
    size_t base = (size_t)wid << 6;
    int myMeta = (lane < cv) ? meta[base + lane] : 0;
    float a0 = 0.f, a1 = 0.f, a2 = 0.f, a3 = 0.f;
    float a4 = 0.f, a5 = 0.f, a6 = 0.f, a7 = 0.f;
    for (int i = g; i < cv; i += 8) {
        int r = __shfl(myMeta, i);
        uint4 v = *((const uint4*)(xwh + ((size_t)r << 6)) + s);
        __half2 h0 = *reinterpret_cast<const __half2*>(&v.x);
        __half2 h1 = *reinterpret_cast<const __half2*>(&v.y);
        __half2 h2 = *reinterpret_cast<const __half2*>(&v.z);
        __half2 h3 = *reinterpret_cast<const __half2*>(&v.w);
        float2 f;
        f = __half22float2(h0); a0 += f.x; a1 += f.y;
        f = __half22float2(h1); a2 += f.x; a3 += f.y;
        f = __half22float2(h2); a4 += f.x; a5 += f.y;
        f = __half22float2(h3); a6 += f.x; a7 += f.y;
    }
#pragma unroll
    for (int m = 8; m <= 32; m <<= 1) {
        a0 += __shfl_xor(a0, m); a1 += __shfl_xor(a1, m);
        a2 += __shfl_xor(a2, m); a3 += __shfl_xor(a3, m);
        a4 += __shfl_xor(a4, m); a5 += __shfl_xor(a5, m);
        a6 += __shfl_xor(a6, m); a7 += __shfl_xor(a7, m);
    }
    if (g == 0) {
        float dc = rsqrtf((float)cv);
        float4 bv0 = ((const float4*)bias)[2 * s];
        float4 bv1 = ((const float4*)bias)[2 * s + 1];
        __half2 o0 = __floats2half2_rn(fmaxf(fmaf(a0, dc, bv0.x), 0.f),
                                       fmaxf(fmaf(a1, dc, bv0.y), 0.f));
        __half2 o1 = __floats2half2_rn(fmaxf(fmaf(a2, dc, bv0.z), 0.f),
                                       fmaxf(fmaf(a3, dc, bv0.w), 0.f));
        __half2 o2 = __floats2half2_rn(fmaxf(fmaf(a4, dc, bv1.x), 0.f),
                                       fmaxf(fmaf(a5, dc, bv1.y), 0.f));
        __half2 o3 = __floats2half2_rn(fmaxf(fmaf(a6, dc, bv1.z), 0.f),
                                       fmaxf(fmaf(a7, dc, bv1.w), 0.f));
        uint4 pk;
        pk.x = *reinterpret_cast<unsigned int*>(&o0);
        pk.y = *reinterpret_cast<unsigned int*>(&o1);
        pk.z = *reinterpret_cast<unsigned int*>(&o2);
        pk.w = *reinterpret_cast<unsigned int*>(&o3);
        *((uint4*)(out + base) + s) = pk;
    }
}

// one block per graph: reduce 16 partials -> pooled (LDS), logits, softmax
__global__ __launch_bounds__(192) void k_head(const float* __restrict__ pooledPart,
                                              const int* __restrict__ batch, int n,
                                              const float* __restrict__ Wf,
                                              const float* __restrict__ bf,
                                              float* __restrict__ out) {
    int g = blockIdx.x;
    __shared__ float pool[FCAT];
    __shared__ float lg[NCLASSES];
    int f = threadIdx.x;
    float s = 0.0f;
#pragma unroll
    for (int p = 0; p < PSPLIT; ++p)
        s += pooledPart[(size_t)(p * NGRAPHS + g) * FCAT + f];
    int lo = 0, hi = n;
    while (lo < hi) { int m = (lo + hi) >> 1; if (batch[m] < g) lo = m + 1; else hi = m; }
    int s0 = lo;
    lo = s0; hi = n;
    while (lo < hi) { int m = (lo + hi) >> 1; if (batch[m] < g + 1) lo = m + 1; else hi = m; }
    float invc = 1.0f / fmaxf((float)(lo - s0), 1.0f);
    pool[f] = s * invc;
    __syncthreads();
    if (f < NCLASSES) {
        float acc = bf[f];
        for (int k = 0; k < FCAT; ++k) acc = fmaf(pool[k], Wf[k * NCLASSES + f], acc);
        lg[f] = acc;
    }
    __syncthreads();
    if (f == 0) {
        float mx = lg[0];
#pragma unroll
        for (int c = 1; c < NCLASSES; ++c) mx = fmaxf(mx, lg[c]);
        float ss = 0.0f;
        float e[NCLASSES];
#pragma unroll
        for (int c = 0; c < NCLASSES; ++c) { e[c] = expf(lg[c] - mx); ss += e[c]; }
        float inv = 1.0f / ss;
#pragma unroll
        for (int c = 0; c < NCLASSES; ++c) out[g * NCLASSES + c] = e[c] * inv;
    }
}

// ---------------------------------------------------------------------------

extern "C" void kernel_launch(void* const* d_in, const int* in_sizes, int n_in,
                              void* d_out, int out_size, void* d_ws, size_t ws_size,
                              hipStream_t stream) {
    const float* features = (const float*)d_in[0];
    const int*   edge     = (const int*)d_in[1];
    const int*   batch    = (const int*)d_in[2];
    const float* W1 = (const float*)d_in[3]; const float* b1 = (const float*)d_in[4];
    const float* W2 = (const float*)d_in[5]; const float* b2 = (const float*)d_in[6];
    const float* W3 = (const float*)d_in[7]; const float* b3 = (const float*)d_in[8];
    const float* Wf = (const float*)d_in[9]; const float* bf = (const float*)d_in[10];
    float* out = (float*)d_out;

    const int n = in_sizes[0] / F;   // 100000
    const int E = in_sizes[1] / 2;   // 1600000
    const int* row = edge;
    const int* col = edge + E;

    // workspace layout
    __half* x0h   = (__half*)d_ws;                     // [n*64] layer3 out
    __half* bufAh = x0h + (size_t)n * F;               // [n*64] layer1 out
    __half* bufBh = bufAh + (size_t)n * F;             // [n*64] layer2 out
    __half* xwh   = bufBh + (size_t)n * F;             // [n*64]
    __half* Wt    = xwh + (size_t)n * F;               // [3*64*64]
    int*    meta  = (int*)(Wt + 3 * F * F);            // [n*CAP]
    int*    slot  = meta + (size_t)n * CAP;            // [E]
    int*    cnt   = slot + E;                          // [n]
    float*  pooledPart = (float*)(cnt + n);            // [16*128*192]

    const int BT = 256;
    int gE  = (E + BT - 1) / BT;           // 6250 count/fill blocks
    int gW  = (n + 3) / 4;                 // gather grid (4 nodes/block)
    int gT  = ((n + 15) / 16 + 3) / 4;     // gemm grid (4 tiles/block)
    int sBlk = (n * 8 + BT - 1) / BT;      // scale blocks (16B/thread)
    int gSelf = (n + BT - 1) / BT;         // self-meta blocks
    const int PB = NGRAPHS * PSPLIT;       // 2048 pool blocks

    // ---- build ----
    k_prep<<<256, BT, 0, stream>>>(W1, W2, W3, cnt, Wt, n);
    k_cntgemm1<<<gE + gT, BT, 0, stream>>>(col, cnt, slot, E, features, Wt,
                                           xwh, n, gT);
    k_fillscale<<<gE + sBlk + gSelf, BT, 0, stream>>>(row, col, slot, E, meta,
                                                      cnt, xwh, n, gE, sBlk);

    // ---- layer 1 gather ----
    k_gather<<<gW, BT, 0, stream>>>(xwh, meta, cnt, b1, bufAh, n);

    // ---- layer 2 gemm ∥ pool(layer1) ----
    k_gemmpool<<<gT + PB, BT, 0, stream>>>(bufAh, Wt + 4096, cnt, xwh, n, gT,
                                           bufAh, batch, pooledPart, 0);
    k_gather<<<gW, BT, 0, stream>>>(xwh, meta, cnt, b2, bufBh, n);

    // ---- layer 3 gemm ∥ pool(layer2) ----
    k_gemmpool<<<gT + PB, BT, 0, stream>>>(bufBh, Wt + 8192, cnt, xwh, n, gT,
                                           bufBh, batch, pooledPart, F);
    k_gather<<<gW, BT, 0, stream>>>(xwh, meta, cnt, b3, x0h, n);

    // ---- pool(layer3) + head ----
    k_pool<<<PB, BT, 0, stream>>>(x0h, batch, n, pooledPart, 2 * F);
    k_head<<<NGRAPHS, FCAT, 0, stream>>>(pooledPart, batch, n, Wf, bf, out);
}